// Round 1
// baseline (7206.814 us; speedup 1.0000x reference)
//
#include <hip/hip_runtime.h>

// ---------------------------------------------------------------------------
// VoxelSetAbstraction forward (PV-RCNN style) for MI355X
//   B=2, N_RAW=16384, N_KP=2048, M_VOX=8192, C_VOX=64
//   BEV: (2,256,200,176), stride 8, voxel 0.05, pc_min (0,-40,-3)
//   raw SA: radii (0.4,0.8) ns (16,16), MLP 4->16->16
//   conv SA: radii (1.2,2.4) ns (16,32), MLP 67->64->64
//   fusion: 416 -> 128
// ---------------------------------------------------------------------------

#define NRAW   16384
#define MVOX   8192
#define NKP    2048
#define NKPALL 4096   // B * NKP

__device__ __constant__ float kBNS = (float)0.9999950000374997; // 1/sqrt(1+1e-5)

// ---------------------------------------------------------------------------
// K0: transpose points to SoA + compute voxel centers
// ---------------------------------------------------------------------------
__global__ __launch_bounds__(256) void prep_kernel(
    const float* __restrict__ pts, const int* __restrict__ vc,
    float* __restrict__ rx, float* __restrict__ ry, float* __restrict__ rz,
    float* __restrict__ rint,
    float* __restrict__ cx, float* __restrict__ cy, float* __restrict__ cz) {
#pragma clang fp contract(off)
  int i = blockIdx.x * 256 + threadIdx.x;
  if (i < 2 * NRAW) {
    const float* p = pts + (size_t)i * 5;
    rx[i] = p[1]; ry[i] = p[2]; rz[i] = p[3]; rint[i] = p[4];
  }
  if (i < 2 * MVOX) {
    const int* v = vc + (size_t)i * 4;
    cx[i] = ((float)v[3] + 0.5f) * 0.2f + 0.0f;
    cy[i] = ((float)v[2] + 0.5f) * 0.2f + -40.0f;
    cz[i] = ((float)v[1] + 0.5f) * 0.4f + -3.0f;
  }
}

// ---------------------------------------------------------------------------
// K1: farthest point sampling, one block per batch, 1024 thr, 16 pts/thread.
// Exactly mirrors the reference: dists=min(dists,d2(last)); next=argmax
// (first-index tiebreak). No FMA so f32 bits match a numpy reference.
// ---------------------------------------------------------------------------
__global__ __launch_bounds__(1024) void fps_kernel(
    const float* __restrict__ rx, const float* __restrict__ ry,
    const float* __restrict__ rz,
    float* __restrict__ kx, float* __restrict__ ky, float* __restrict__ kz) {
#pragma clang fp contract(off)
  const int b = blockIdx.x;
  const int t = threadIdx.x;
  const float* bxp = rx + b * NRAW;
  const float* byp = ry + b * NRAW;
  const float* bzp = rz + b * NRAW;

  float px[16], py[16], pz[16], dd[16];
#pragma unroll
  for (int j = 0; j < 16; ++j) {
    int p = j * 1024 + t;
    px[j] = bxp[p]; py[j] = byp[p]; pz[j] = bzp[p];
    dd[j] = 1e10f;
  }

  __shared__ float s_wv[16], s_wx[16], s_wy[16], s_wz[16];
  __shared__ int   s_wi[16];
  __shared__ float s_lx, s_ly, s_lz;

  if (t == 0) {
    kx[b * NKP] = px[0]; ky[b * NKP] = py[0]; kz[b * NKP] = pz[0];
    s_lx = px[0]; s_ly = py[0]; s_lz = pz[0];
  }
  __syncthreads();

  for (int s = 1; s < NKP; ++s) {
    const float lx = s_lx, ly = s_ly, lz = s_lz;
    float bv = -1.0f, bx = 0.f, by = 0.f, bz = 0.f;
    int bi = 0;
#pragma unroll
    for (int j = 0; j < 16; ++j) {
      float dx = px[j] - lx, dy = py[j] - ly, dz = pz[j] - lz;
      float d2 = dx * dx; d2 = d2 + dy * dy; d2 = d2 + dz * dz;
      float nd = fminf(dd[j], d2);
      dd[j] = nd;
      if (nd > bv) { bv = nd; bi = j * 1024 + t; bx = px[j]; by = py[j]; bz = pz[j]; }
    }
    // wave (64-lane) argmax reduce, first-index tiebreak
#pragma unroll
    for (int off = 1; off < 64; off <<= 1) {
      float ov = __shfl_xor(bv, off, 64);
      int   oi = __shfl_xor(bi, off, 64);
      float ox = __shfl_xor(bx, off, 64);
      float oy = __shfl_xor(by, off, 64);
      float oz = __shfl_xor(bz, off, 64);
      if (ov > bv || (ov == bv && oi < bi)) { bv = ov; bi = oi; bx = ox; by = oy; bz = oz; }
    }
    if ((t & 63) == 0) {
      int w = t >> 6;
      s_wv[w] = bv; s_wi[w] = bi; s_wx[w] = bx; s_wy[w] = by; s_wz[w] = bz;
    }
    __syncthreads();
    if (t == 0) {
      float v = s_wv[0]; int i0 = s_wi[0];
      float X = s_wx[0], Y = s_wy[0], Z = s_wz[0];
      for (int w = 1; w < 16; ++w) {
        float wv = s_wv[w]; int wi = s_wi[w];
        if (wv > v || (wv == v && wi < i0)) { v = wv; i0 = wi; X = s_wx[w]; Y = s_wy[w]; Z = s_wz[w]; }
      }
      s_lx = X; s_ly = Y; s_lz = Z;
      kx[b * NKP + s] = X; ky[b * NKP + s] = Y; kz[b * NKP + s] = Z;
    }
    __syncthreads();
  }
}

// ---------------------------------------------------------------------------
// K2: BEV bilinear. one block per keypoint, 256 threads = 256 channels.
// ---------------------------------------------------------------------------
__global__ __launch_bounds__(256) void bev_kernel(
    const float* __restrict__ sf, const float* __restrict__ kx,
    const float* __restrict__ ky, float* __restrict__ feats) {
#pragma clang fp contract(off)
  const int kidx = blockIdx.x;
  const int c = threadIdx.x;
  const int b = kidx >> 11;
  const float x = (kx[kidx] - 0.0f) / 0.05f / 8.0f;
  const float y = (ky[kidx] - (-40.0f)) / 0.05f / 8.0f;
  const float xf = floorf(x), yf = floorf(y);
  int x0 = (int)xf;     x0 = x0 < 0 ? 0 : (x0 > 175 ? 175 : x0);
  int x1 = (int)xf + 1; x1 = x1 < 0 ? 0 : (x1 > 175 ? 175 : x1);
  int y0 = (int)yf;     y0 = y0 < 0 ? 0 : (y0 > 199 ? 199 : y0);
  int y1 = (int)yf + 1; y1 = y1 < 0 ? 0 : (y1 > 199 ? 199 : y1);
  const float x0f = (float)x0, x1f = (float)x1, y0f = (float)y0, y1f = (float)y1;
  const float wa = (x - x0f) * (y1f - y);
  const float wb = (x1f - x) * (y1f - y);
  const float wc = (x1f - x) * (y - y0f);
  const float wd = (x - x0f) * (y - y0f);
  const float* base = sf + ((size_t)b * 256 + c) * (200 * 176);
  const float fa = base[y1 * 176 + x0];
  const float fb = base[y1 * 176 + x1];
  const float fc = base[y0 * 176 + x1];
  const float fd = base[y0 * 176 + x0];
  float r = fd * wb; r = r + fc * wa; r = r + fa * wc; r = r + fb * wd;
  feats[(size_t)kidx * 416 + c] = r;
}

// ---------------------------------------------------------------------------
// K3: raw SA. one wave per (keypoint, radius). MLP 4->16->16, max-pool.
// ---------------------------------------------------------------------------
__global__ __launch_bounds__(256) void raw_sa_kernel(
    const float* __restrict__ rx, const float* __restrict__ ry,
    const float* __restrict__ rz, const float* __restrict__ rint,
    const float* __restrict__ kx, const float* __restrict__ ky,
    const float* __restrict__ kz,
    const float* __restrict__ w0, const float* __restrict__ g0,
    const float* __restrict__ b0, const float* __restrict__ w1,
    const float* __restrict__ g1, const float* __restrict__ b1,
    float* __restrict__ feats) {
  const int wv = threadIdx.x >> 6;
  const int lane = threadIdx.x & 63;
  const int gw = blockIdx.x * 4 + wv;       // 0..8191
  const int ri = gw >> 12;                  // radius index 0/1
  const int kidx = gw & 4095;
  const int b = kidx >> 11;
  const float R2 = ri ? (float)(0.8 * 0.8) : (float)(0.4 * 0.4);

  __shared__ int   idxl[4][16];
  __shared__ float hbuf[4][16][17];

  const float kxv = kx[kidx], kyv = ky[kidx], kzv = kz[kidx];
  const int base = b * NRAW;
  int cnt = 0;
  {
#pragma clang fp contract(off)
    for (int ch = 0; ch < NRAW / 64 && cnt < 16; ++ch) {
      const int p = base + ch * 64 + lane;
      float dx = kxv - rx[p], dy = kyv - ry[p], dz = kzv - rz[p];
      float d2 = dx * dx; d2 = d2 + dy * dy; d2 = d2 + dz * dz;
      unsigned long long m = __ballot(d2 < R2);
      while (m && cnt < 16) {
        int bit = __builtin_ctzll(m);
        if (lane == 0) idxl[wv][cnt] = ch * 64 + bit;
        ++cnt;
        m &= m - 1;
      }
    }
  }
  const int outoff = kidx * 416 + 256 + ri * 16;
  if (cnt == 0) {
    if (lane < 16) feats[outoff + lane] = 0.f;
    return;
  }
  __threadfence_block();

  const int s = lane & 15, cq = lane >> 4;
  const int ss = (s < cnt) ? s : 0;          // duplicate sample 0 (matches ref pad)
  const int p = base + idxl[wv][ss];
  const float gx = rx[p] - kxv, gy = ry[p] - kyv, gz = rz[p] - kzv, gi = rint[p];
  const int wb0 = ri * 64, cb = ri * 16;
#pragma unroll
  for (int j = 0; j < 4; ++j) {
    int c = cq * 4 + j;
    float a = gx * w0[wb0 + c];
    a = fmaf(gy, w0[wb0 + 16 + c], a);
    a = fmaf(gz, w0[wb0 + 32 + c], a);
    a = fmaf(gi, w0[wb0 + 48 + c], a);
    a = fmaf(a, g0[cb + c] * kBNS, b0[cb + c]);
    hbuf[wv][s][c] = fmaxf(a, 0.f);
  }
  __threadfence_block();
  float o0 = 0.f, o1 = 0.f, o2 = 0.f, o3 = 0.f;
  const int wb1 = ri * 256;
#pragma unroll
  for (int k = 0; k < 16; ++k) {
    float hk = hbuf[wv][s][k];
    o0 = fmaf(hk, w1[wb1 + k * 16 + cq * 4 + 0], o0);
    o1 = fmaf(hk, w1[wb1 + k * 16 + cq * 4 + 1], o1);
    o2 = fmaf(hk, w1[wb1 + k * 16 + cq * 4 + 2], o2);
    o3 = fmaf(hk, w1[wb1 + k * 16 + cq * 4 + 3], o3);
  }
  float v0 = fmaxf(fmaf(o0, g1[cb + cq * 4 + 0] * kBNS, b1[cb + cq * 4 + 0]), 0.f);
  float v1 = fmaxf(fmaf(o1, g1[cb + cq * 4 + 1] * kBNS, b1[cb + cq * 4 + 1]), 0.f);
  float v2 = fmaxf(fmaf(o2, g1[cb + cq * 4 + 2] * kBNS, b1[cb + cq * 4 + 2]), 0.f);
  float v3 = fmaxf(fmaf(o3, g1[cb + cq * 4 + 3] * kBNS, b1[cb + cq * 4 + 3]), 0.f);
#pragma unroll
  for (int off = 1; off < 16; off <<= 1) {
    v0 = fmaxf(v0, __shfl_xor(v0, off, 64));
    v1 = fmaxf(v1, __shfl_xor(v1, off, 64));
    v2 = fmaxf(v2, __shfl_xor(v2, off, 64));
    v3 = fmaxf(v3, __shfl_xor(v3, off, 64));
  }
  if (s == 0) {
    feats[outoff + cq * 4 + 0] = v0;
    feats[outoff + cq * 4 + 1] = v1;
    feats[outoff + cq * 4 + 2] = v2;
    feats[outoff + cq * 4 + 3] = v3;
  }
}

// ---------------------------------------------------------------------------
// K4: conv SA. one wave per (keypoint, radius). MLP 67->64->64, max-pool.
// Weight columns live in VGPRs; grouped feature row broadcast via LDS.
// ---------------------------------------------------------------------------
__global__ __launch_bounds__(256) void conv_sa_kernel(
    const float* __restrict__ cx, const float* __restrict__ cy,
    const float* __restrict__ cz, const float* __restrict__ vf,
    const float* __restrict__ kx, const float* __restrict__ ky,
    const float* __restrict__ kz,
    const float* __restrict__ w0, const float* __restrict__ g0,
    const float* __restrict__ b0, const float* __restrict__ w1,
    const float* __restrict__ g1, const float* __restrict__ b1,
    float* __restrict__ feats) {
  const int wv = threadIdx.x >> 6;
  const int lane = threadIdx.x & 63;
  const int gw = blockIdx.x * 4 + wv;
  const int ri = gw >> 12;
  const int kidx = gw & 4095;
  const int b = kidx >> 11;
  const int NS = ri ? 32 : 16;
  const float R2 = ri ? (float)(2.4 * 2.4) : (float)(1.2 * 1.2);

  __shared__ int   idxl[4][32];
  __shared__ float gbuf[4][64];
  __shared__ float hbuf[4][32][64];

  const float kxv = kx[kidx], kyv = ky[kidx], kzv = kz[kidx];
  const int base = b * MVOX;
  int cnt = 0;
  {
#pragma clang fp contract(off)
    for (int ch = 0; ch < MVOX / 64 && cnt < NS; ++ch) {
      const int p = base + ch * 64 + lane;
      float dx = kxv - cx[p], dy = kyv - cy[p], dz = kzv - cz[p];
      float d2 = dx * dx; d2 = d2 + dy * dy; d2 = d2 + dz * dz;
      unsigned long long m = __ballot(d2 < R2);
      while (m && cnt < NS) {
        int bit = __builtin_ctzll(m);
        if (lane == 0) idxl[wv][cnt] = ch * 64 + bit;
        ++cnt;
        m &= m - 1;
      }
    }
  }
  const int outoff = kidx * 416 + 288 + ri * 64;
  if (cnt == 0) {
    feats[outoff + lane] = 0.f;
    return;
  }
  __threadfence_block();

  // per-lane weight columns (lane == output channel)
  const float wA0 = w0[(ri * 67 + 0) * 64 + lane];
  const float wA1 = w0[(ri * 67 + 1) * 64 + lane];
  const float wA2 = w0[(ri * 67 + 2) * 64 + lane];
  float wB[64];
#pragma unroll
  for (int k = 0; k < 64; ++k) wB[k] = w0[(ri * 67 + 3 + k) * 64 + lane];
  float wC[64];
#pragma unroll
  for (int k = 0; k < 64; ++k) wC[k] = w1[(ri * 64 + k) * 64 + lane];
  const float s0 = g0[ri * 64 + lane] * kBNS, bb0 = b0[ri * 64 + lane];
  const float s1 = g1[ri * 64 + lane] * kBNS, bb1 = b1[ri * 64 + lane];

  for (int sm = 0; sm < cnt; ++sm) {
    const int p = base + idxl[wv][sm];
    const float ox = cx[p] - kxv, oy = cy[p] - kyv, oz = cz[p] - kzv;
    gbuf[wv][lane] = vf[(size_t)p * 64 + lane];
    __threadfence_block();
    float acc = ox * wA0;
    acc = fmaf(oy, wA1, acc);
    acc = fmaf(oz, wA2, acc);
#pragma unroll
    for (int k4 = 0; k4 < 16; ++k4) {
      float4 g4 = *(const float4*)&gbuf[wv][k4 * 4];
      acc = fmaf(g4.x, wB[k4 * 4 + 0], acc);
      acc = fmaf(g4.y, wB[k4 * 4 + 1], acc);
      acc = fmaf(g4.z, wB[k4 * 4 + 2], acc);
      acc = fmaf(g4.w, wB[k4 * 4 + 3], acc);
    }
    hbuf[wv][sm][lane] = fmaxf(fmaf(acc, s0, bb0), 0.f);
    __threadfence_block();
  }
  float mx = -1e30f;
  for (int sm = 0; sm < cnt; ++sm) {
    float acc = 0.f;
#pragma unroll
    for (int k4 = 0; k4 < 16; ++k4) {
      float4 h4 = *(const float4*)&hbuf[wv][sm][k4 * 4];
      acc = fmaf(h4.x, wC[k4 * 4 + 0], acc);
      acc = fmaf(h4.y, wC[k4 * 4 + 1], acc);
      acc = fmaf(h4.z, wC[k4 * 4 + 2], acc);
      acc = fmaf(h4.w, wC[k4 * 4 + 3], acc);
    }
    mx = fmaxf(mx, fmaxf(fmaf(acc, s1, bb1), 0.f));
  }
  feats[outoff + lane] = mx;
}

// ---------------------------------------------------------------------------
// K5: fusion 416 -> 128 + BN + ReLU. one thread per (kp, out-channel).
// ---------------------------------------------------------------------------
__global__ __launch_bounds__(256) void fusion_kernel(
    const float* __restrict__ feats, const float* __restrict__ fw,
    const float* __restrict__ fg, const float* __restrict__ fb,
    float* __restrict__ out) {
  const int gid = blockIdx.x * 256 + threadIdx.x;
  const int kidx = gid >> 7, c = gid & 127;
  const float* f = feats + (size_t)kidx * 416;
  float acc = 0.f;
#pragma unroll 4
  for (int k = 0; k < 416; k += 4) {
    float4 fv = *(const float4*)(f + k);
    acc = fmaf(fv.x, fw[(k + 0) * 128 + c], acc);
    acc = fmaf(fv.y, fw[(k + 1) * 128 + c], acc);
    acc = fmaf(fv.z, fw[(k + 2) * 128 + c], acc);
    acc = fmaf(fv.w, fw[(k + 3) * 128 + c], acc);
  }
  out[gid] = fmaxf(fmaf(acc, fg[c] * kBNS, fb[c]), 0.f);
}

// ---------------------------------------------------------------------------
extern "C" void kernel_launch(void* const* d_in, const int* in_sizes, int n_in,
                              void* d_out, int out_size, void* d_ws, size_t ws_size,
                              hipStream_t stream) {
  (void)in_sizes; (void)n_in; (void)out_size; (void)ws_size;
  const float* pts = (const float*)d_in[0];
  const float* sf  = (const float*)d_in[1];
  const int*   vc  = (const int*)d_in[2];
  const float* vf  = (const float*)d_in[3];
  const float* raw_w0 = (const float*)d_in[4];
  const float* raw_g0 = (const float*)d_in[5];
  const float* raw_b0 = (const float*)d_in[6];
  const float* raw_w1 = (const float*)d_in[7];
  const float* raw_g1 = (const float*)d_in[8];
  const float* raw_b1 = (const float*)d_in[9];
  const float* conv_w0 = (const float*)d_in[10];
  const float* conv_g0 = (const float*)d_in[11];
  const float* conv_b0 = (const float*)d_in[12];
  const float* conv_w1 = (const float*)d_in[13];
  const float* conv_g1 = (const float*)d_in[14];
  const float* conv_b1 = (const float*)d_in[15];
  const float* fus_w = (const float*)d_in[16];
  const float* fus_g = (const float*)d_in[17];
  const float* fus_b = (const float*)d_in[18];
  float* out = (float*)d_out;

  float* W = (float*)d_ws;
  float* rx   = W;            // 32768
  float* ry   = W + 32768;
  float* rz   = W + 65536;
  float* rint = W + 98304;
  float* cx   = W + 131072;   // 16384 each
  float* cy   = W + 147456;
  float* cz   = W + 163840;
  float* kx   = W + 180224;   // 4096 each
  float* ky   = W + 184320;
  float* kz   = W + 188416;
  float* feats = W + 192512;  // 4096 * 416

  prep_kernel<<<128, 256, 0, stream>>>(pts, vc, rx, ry, rz, rint, cx, cy, cz);
  fps_kernel<<<2, 1024, 0, stream>>>(rx, ry, rz, kx, ky, kz);
  bev_kernel<<<NKPALL, 256, 0, stream>>>(sf, kx, ky, feats);
  raw_sa_kernel<<<2048, 256, 0, stream>>>(rx, ry, rz, rint, kx, ky, kz,
                                          raw_w0, raw_g0, raw_b0, raw_w1, raw_g1, raw_b1,
                                          feats);
  conv_sa_kernel<<<2048, 256, 0, stream>>>(cx, cy, cz, vf, kx, ky, kz,
                                           conv_w0, conv_g0, conv_b0, conv_w1, conv_g1, conv_b1,
                                           feats);
  fusion_kernel<<<2048, 256, 0, stream>>>(feats, fus_w, fus_g, fus_b, out);
}

// Round 2
// 6207.676 us; speedup vs baseline: 1.1610x; 1.1610x over previous
//
#include <hip/hip_runtime.h>

// ---------------------------------------------------------------------------
// VoxelSetAbstraction forward (PV-RCNN style) for MI355X
//   B=2, N_RAW=16384, N_KP=2048, M_VOX=8192, C_VOX=64
//   BEV: (2,256,200,176), stride 8, voxel 0.05, pc_min (0,-40,-3)
//   raw SA: radii (0.4,0.8) ns (16,16), MLP 4->16->16
//   conv SA: radii (1.2,2.4) ns (16,32), MLP 67->64->64
//   fusion: 416 -> 128
// ---------------------------------------------------------------------------

#define NRAW   16384
#define MVOX   8192
#define NKP    2048
#define NKPALL 4096   // B * NKP

__device__ __constant__ float kBNS = (float)0.9999950000374997; // 1/sqrt(1+1e-5)

// ---------------------------------------------------------------------------
// K0: transpose points to SoA + compute voxel centers
// ---------------------------------------------------------------------------
__global__ __launch_bounds__(256) void prep_kernel(
    const float* __restrict__ pts, const int* __restrict__ vc,
    float* __restrict__ rx, float* __restrict__ ry, float* __restrict__ rz,
    float* __restrict__ rint,
    float* __restrict__ cx, float* __restrict__ cy, float* __restrict__ cz) {
#pragma clang fp contract(off)
  int i = blockIdx.x * 256 + threadIdx.x;
  if (i < 2 * NRAW) {
    const float* p = pts + (size_t)i * 5;
    rx[i] = p[1]; ry[i] = p[2]; rz[i] = p[3]; rint[i] = p[4];
  }
  if (i < 2 * MVOX) {
    const int* v = vc + (size_t)i * 4;
    cx[i] = ((float)v[3] + 0.5f) * 0.2f + 0.0f;
    cy[i] = ((float)v[2] + 0.5f) * 0.2f + -40.0f;
    cz[i] = ((float)v[1] + 0.5f) * 0.4f + -3.0f;
  }
}

// ---------------------------------------------------------------------------
// K1: farthest point sampling. One block/batch, 1024 thr, 16 pts/thread in
// VGPRs (launch_bounds(1024,4) -> 128-VGPR budget, no AGPR shuffling).
// Per iteration (2047 total, strictly sequential):
//   - register dist-update + local argmax (contract off, exact numpy order)
//   - wave reduce of (packed u64 = f32bits<<32 | ~idx, x, y, z); u64 max
//     == max val, first-index tiebreak (dists >= 0 so f32 bits order as uint)
//   - lane0 -> LDS[16] (double-buffered), ONE barrier
//   - all lanes: read entry lane&15, 4-stage shfl_xor reduce -> every thread
//     holds winner coords in registers (no serial scan, no 2nd barrier)
// ---------------------------------------------------------------------------
__global__ __launch_bounds__(1024, 4) void fps_kernel(
    const float* __restrict__ rx, const float* __restrict__ ry,
    const float* __restrict__ rz,
    float* __restrict__ kx, float* __restrict__ ky, float* __restrict__ kz) {
#pragma clang fp contract(off)
  const int b = blockIdx.x;
  const int t = threadIdx.x;
  const float* bxp = rx + b * NRAW;
  const float* byp = ry + b * NRAW;
  const float* bzp = rz + b * NRAW;

  float px[16], py[16], pz[16], dd[16];
#pragma unroll
  for (int j = 0; j < 16; ++j) {
    int p = j * 1024 + t;
    px[j] = bxp[p]; py[j] = byp[p]; pz[j] = bzp[p];
    dd[j] = 1e10f;
  }

  // winner state for iteration 0: point 0 (uniform broadcast load)
  float lx = bxp[0], ly = byp[0], lz = bzp[0];
  if (t == 0) { kx[b * NKP] = lx; ky[b * NKP] = ly; kz[b * NKP] = lz; }

  __shared__ unsigned long long s_pk[2][16];
  __shared__ float s_sx[2][16], s_sy[2][16], s_sz[2][16];

  for (int s = 1; s < NKP; ++s) {
    const int buf = s & 1;
    float bv = -1.0f, wx = 0.f, wy = 0.f, wz = 0.f;
    int bi = 0;
#pragma unroll
    for (int j = 0; j < 16; ++j) {
      float dx = px[j] - lx, dy = py[j] - ly, dz = pz[j] - lz;
      float d2 = dx * dx; d2 = d2 + dy * dy; d2 = d2 + dz * dz;
      float nd = fminf(dd[j], d2);
      dd[j] = nd;
      bool c = nd > bv;                    // ascending j => first-idx tiebreak
      bv = c ? nd : bv;
      bi = c ? (j * 1024 + t) : bi;
      wx = c ? px[j] : wx; wy = c ? py[j] : wy; wz = c ? pz[j] : wz;
    }
    unsigned long long pk =
        ((unsigned long long)__float_as_uint(bv) << 32) | (unsigned)(~bi);
    // 64-lane reduce: max packed (val, min idx), carry coords
#pragma unroll
    for (int off = 1; off < 64; off <<= 1) {
      unsigned long long opk = __shfl_xor(pk, off, 64);
      float ox = __shfl_xor(wx, off, 64);
      float oy = __shfl_xor(wy, off, 64);
      float oz = __shfl_xor(wz, off, 64);
      if (opk > pk) { pk = opk; wx = ox; wy = oy; wz = oz; }
    }
    if ((t & 63) == 0) {
      int w = t >> 6;
      s_pk[buf][w] = pk; s_sx[buf][w] = wx; s_sy[buf][w] = wy; s_sz[buf][w] = wz;
    }
    __syncthreads();
    // every lane reads entry (lane&15); 4-stage butterfly -> global winner
    const int e = t & 15;
    unsigned long long p2 = s_pk[buf][e];
    float qx = s_sx[buf][e], qy = s_sy[buf][e], qz = s_sz[buf][e];
#pragma unroll
    for (int off = 1; off < 16; off <<= 1) {
      unsigned long long o2 = __shfl_xor(p2, off, 64);
      float ox = __shfl_xor(qx, off, 64);
      float oy = __shfl_xor(qy, off, 64);
      float oz = __shfl_xor(qz, off, 64);
      if (o2 > p2) { p2 = o2; qx = ox; qy = oy; qz = oz; }
    }
    lx = qx; ly = qy; lz = qz;
    if (t == 0) { kx[b * NKP + s] = lx; ky[b * NKP + s] = ly; kz[b * NKP + s] = lz; }
    // no second barrier: next iter writes the other LDS buffer; a wave
    // cannot be >1 barrier ahead, so reads of buf finish before re-write.
  }
}

// ---------------------------------------------------------------------------
// K2: BEV bilinear. one block per keypoint, 256 threads = 256 channels.
// ---------------------------------------------------------------------------
__global__ __launch_bounds__(256) void bev_kernel(
    const float* __restrict__ sf, const float* __restrict__ kx,
    const float* __restrict__ ky, float* __restrict__ feats) {
#pragma clang fp contract(off)
  const int kidx = blockIdx.x;
  const int c = threadIdx.x;
  const int b = kidx >> 11;
  const float x = (kx[kidx] - 0.0f) / 0.05f / 8.0f;
  const float y = (ky[kidx] - (-40.0f)) / 0.05f / 8.0f;
  const float xf = floorf(x), yf = floorf(y);
  int x0 = (int)xf;     x0 = x0 < 0 ? 0 : (x0 > 175 ? 175 : x0);
  int x1 = (int)xf + 1; x1 = x1 < 0 ? 0 : (x1 > 175 ? 175 : x1);
  int y0 = (int)yf;     y0 = y0 < 0 ? 0 : (y0 > 199 ? 199 : y0);
  int y1 = (int)yf + 1; y1 = y1 < 0 ? 0 : (y1 > 199 ? 199 : y1);
  const float x0f = (float)x0, x1f = (float)x1, y0f = (float)y0, y1f = (float)y1;
  const float wa = (x - x0f) * (y1f - y);
  const float wb = (x1f - x) * (y1f - y);
  const float wc = (x1f - x) * (y - y0f);
  const float wd = (x - x0f) * (y - y0f);
  const float* base = sf + ((size_t)b * 256 + c) * (200 * 176);
  const float fa = base[y1 * 176 + x0];
  const float fb = base[y1 * 176 + x1];
  const float fc = base[y0 * 176 + x1];
  const float fd = base[y0 * 176 + x0];
  float r = fd * wb; r = r + fc * wa; r = r + fa * wc; r = r + fb * wd;
  feats[(size_t)kidx * 416 + c] = r;
}

// ---------------------------------------------------------------------------
// K3: raw SA. one wave per (keypoint, radius). MLP 4->16->16, max-pool.
// ---------------------------------------------------------------------------
__global__ __launch_bounds__(256) void raw_sa_kernel(
    const float* __restrict__ rx, const float* __restrict__ ry,
    const float* __restrict__ rz, const float* __restrict__ rint,
    const float* __restrict__ kx, const float* __restrict__ ky,
    const float* __restrict__ kz,
    const float* __restrict__ w0, const float* __restrict__ g0,
    const float* __restrict__ b0, const float* __restrict__ w1,
    const float* __restrict__ g1, const float* __restrict__ b1,
    float* __restrict__ feats) {
  const int wv = threadIdx.x >> 6;
  const int lane = threadIdx.x & 63;
  const int gw = blockIdx.x * 4 + wv;       // 0..8191
  const int ri = gw >> 12;                  // radius index 0/1
  const int kidx = gw & 4095;
  const int b = kidx >> 11;
  const float R2 = ri ? (float)(0.8 * 0.8) : (float)(0.4 * 0.4);

  __shared__ int   idxl[4][16];
  __shared__ float hbuf[4][16][17];

  const float kxv = kx[kidx], kyv = ky[kidx], kzv = kz[kidx];
  const int base = b * NRAW;
  int cnt = 0;
  {
#pragma clang fp contract(off)
    for (int ch = 0; ch < NRAW / 64 && cnt < 16; ++ch) {
      const int p = base + ch * 64 + lane;
      float dx = kxv - rx[p], dy = kyv - ry[p], dz = kzv - rz[p];
      float d2 = dx * dx; d2 = d2 + dy * dy; d2 = d2 + dz * dz;
      unsigned long long m = __ballot(d2 < R2);
      while (m && cnt < 16) {
        int bit = __builtin_ctzll(m);
        if (lane == 0) idxl[wv][cnt] = ch * 64 + bit;
        ++cnt;
        m &= m - 1;
      }
    }
  }
  const int outoff = kidx * 416 + 256 + ri * 16;
  if (cnt == 0) {
    if (lane < 16) feats[outoff + lane] = 0.f;
    return;
  }
  __threadfence_block();

  const int s = lane & 15, cq = lane >> 4;
  const int ss = (s < cnt) ? s : 0;          // duplicate sample 0 (matches ref pad)
  const int p = base + idxl[wv][ss];
  const float gx = rx[p] - kxv, gy = ry[p] - kyv, gz = rz[p] - kzv, gi = rint[p];
  const int wb0 = ri * 64, cb = ri * 16;
#pragma unroll
  for (int j = 0; j < 4; ++j) {
    int c = cq * 4 + j;
    float a = gx * w0[wb0 + c];
    a = fmaf(gy, w0[wb0 + 16 + c], a);
    a = fmaf(gz, w0[wb0 + 32 + c], a);
    a = fmaf(gi, w0[wb0 + 48 + c], a);
    a = fmaf(a, g0[cb + c] * kBNS, b0[cb + c]);
    hbuf[wv][s][c] = fmaxf(a, 0.f);
  }
  __threadfence_block();
  float o0 = 0.f, o1 = 0.f, o2 = 0.f, o3 = 0.f;
  const int wb1 = ri * 256;
#pragma unroll
  for (int k = 0; k < 16; ++k) {
    float hk = hbuf[wv][s][k];
    o0 = fmaf(hk, w1[wb1 + k * 16 + cq * 4 + 0], o0);
    o1 = fmaf(hk, w1[wb1 + k * 16 + cq * 4 + 1], o1);
    o2 = fmaf(hk, w1[wb1 + k * 16 + cq * 4 + 2], o2);
    o3 = fmaf(hk, w1[wb1 + k * 16 + cq * 4 + 3], o3);
  }
  float v0 = fmaxf(fmaf(o0, g1[cb + cq * 4 + 0] * kBNS, b1[cb + cq * 4 + 0]), 0.f);
  float v1 = fmaxf(fmaf(o1, g1[cb + cq * 4 + 1] * kBNS, b1[cb + cq * 4 + 1]), 0.f);
  float v2 = fmaxf(fmaf(o2, g1[cb + cq * 4 + 2] * kBNS, b1[cb + cq * 4 + 2]), 0.f);
  float v3 = fmaxf(fmaf(o3, g1[cb + cq * 4 + 3] * kBNS, b1[cb + cq * 4 + 3]), 0.f);
#pragma unroll
  for (int off = 1; off < 16; off <<= 1) {
    v0 = fmaxf(v0, __shfl_xor(v0, off, 64));
    v1 = fmaxf(v1, __shfl_xor(v1, off, 64));
    v2 = fmaxf(v2, __shfl_xor(v2, off, 64));
    v3 = fmaxf(v3, __shfl_xor(v3, off, 64));
  }
  if (s == 0) {
    feats[outoff + cq * 4 + 0] = v0;
    feats[outoff + cq * 4 + 1] = v1;
    feats[outoff + cq * 4 + 2] = v2;
    feats[outoff + cq * 4 + 3] = v3;
  }
}

// ---------------------------------------------------------------------------
// K4: conv SA. one wave per (keypoint, radius). MLP 67->64->64, max-pool.
// Weight columns live in VGPRs; grouped feature row broadcast via LDS.
// ---------------------------------------------------------------------------
__global__ __launch_bounds__(256) void conv_sa_kernel(
    const float* __restrict__ cx, const float* __restrict__ cy,
    const float* __restrict__ cz, const float* __restrict__ vf,
    const float* __restrict__ kx, const float* __restrict__ ky,
    const float* __restrict__ kz,
    const float* __restrict__ w0, const float* __restrict__ g0,
    const float* __restrict__ b0, const float* __restrict__ w1,
    const float* __restrict__ g1, const float* __restrict__ b1,
    float* __restrict__ feats) {
  const int wv = threadIdx.x >> 6;
  const int lane = threadIdx.x & 63;
  const int gw = blockIdx.x * 4 + wv;
  const int ri = gw >> 12;
  const int kidx = gw & 4095;
  const int b = kidx >> 11;
  const int NS = ri ? 32 : 16;
  const float R2 = ri ? (float)(2.4 * 2.4) : (float)(1.2 * 1.2);

  __shared__ int   idxl[4][32];
  __shared__ float gbuf[4][64];
  __shared__ float hbuf[4][32][64];

  const float kxv = kx[kidx], kyv = ky[kidx], kzv = kz[kidx];
  const int base = b * MVOX;
  int cnt = 0;
  {
#pragma clang fp contract(off)
    for (int ch = 0; ch < MVOX / 64 && cnt < NS; ++ch) {
      const int p = base + ch * 64 + lane;
      float dx = kxv - cx[p], dy = kyv - cy[p], dz = kzv - cz[p];
      float d2 = dx * dx; d2 = d2 + dy * dy; d2 = d2 + dz * dz;
      unsigned long long m = __ballot(d2 < R2);
      while (m && cnt < NS) {
        int bit = __builtin_ctzll(m);
        if (lane == 0) idxl[wv][cnt] = ch * 64 + bit;
        ++cnt;
        m &= m - 1;
      }
    }
  }
  const int outoff = kidx * 416 + 288 + ri * 64;
  if (cnt == 0) {
    feats[outoff + lane] = 0.f;
    return;
  }
  __threadfence_block();

  // per-lane weight columns (lane == output channel)
  const float wA0 = w0[(ri * 67 + 0) * 64 + lane];
  const float wA1 = w0[(ri * 67 + 1) * 64 + lane];
  const float wA2 = w0[(ri * 67 + 2) * 64 + lane];
  float wB[64];
#pragma unroll
  for (int k = 0; k < 64; ++k) wB[k] = w0[(ri * 67 + 3 + k) * 64 + lane];
  float wC[64];
#pragma unroll
  for (int k = 0; k < 64; ++k) wC[k] = w1[(ri * 64 + k) * 64 + lane];
  const float s0 = g0[ri * 64 + lane] * kBNS, bb0 = b0[ri * 64 + lane];
  const float s1 = g1[ri * 64 + lane] * kBNS, bb1 = b1[ri * 64 + lane];

  for (int sm = 0; sm < cnt; ++sm) {
    const int p = base + idxl[wv][sm];
    const float ox = cx[p] - kxv, oy = cy[p] - kyv, oz = cz[p] - kzv;
    gbuf[wv][lane] = vf[(size_t)p * 64 + lane];
    __threadfence_block();
    float acc = ox * wA0;
    acc = fmaf(oy, wA1, acc);
    acc = fmaf(oz, wA2, acc);
#pragma unroll
    for (int k4 = 0; k4 < 16; ++k4) {
      float4 g4 = *(const float4*)&gbuf[wv][k4 * 4];
      acc = fmaf(g4.x, wB[k4 * 4 + 0], acc);
      acc = fmaf(g4.y, wB[k4 * 4 + 1], acc);
      acc = fmaf(g4.z, wB[k4 * 4 + 2], acc);
      acc = fmaf(g4.w, wB[k4 * 4 + 3], acc);
    }
    hbuf[wv][sm][lane] = fmaxf(fmaf(acc, s0, bb0), 0.f);
    __threadfence_block();
  }
  float mx = -1e30f;
  for (int sm = 0; sm < cnt; ++sm) {
    float acc = 0.f;
#pragma unroll
    for (int k4 = 0; k4 < 16; ++k4) {
      float4 h4 = *(const float4*)&hbuf[wv][sm][k4 * 4];
      acc = fmaf(h4.x, wC[k4 * 4 + 0], acc);
      acc = fmaf(h4.y, wC[k4 * 4 + 1], acc);
      acc = fmaf(h4.z, wC[k4 * 4 + 2], acc);
      acc = fmaf(h4.w, wC[k4 * 4 + 3], acc);
    }
    mx = fmaxf(mx, fmaxf(fmaf(acc, s1, bb1), 0.f));
  }
  feats[outoff + lane] = mx;
}

// ---------------------------------------------------------------------------
// K5: fusion 416 -> 128 + BN + ReLU. one thread per (kp, out-channel).
// ---------------------------------------------------------------------------
__global__ __launch_bounds__(256) void fusion_kernel(
    const float* __restrict__ feats, const float* __restrict__ fw,
    const float* __restrict__ fg, const float* __restrict__ fb,
    float* __restrict__ out) {
  const int gid = blockIdx.x * 256 + threadIdx.x;
  const int kidx = gid >> 7, c = gid & 127;
  const float* f = feats + (size_t)kidx * 416;
  float acc = 0.f;
#pragma unroll 4
  for (int k = 0; k < 416; k += 4) {
    float4 fv = *(const float4*)(f + k);
    acc = fmaf(fv.x, fw[(k + 0) * 128 + c], acc);
    acc = fmaf(fv.y, fw[(k + 1) * 128 + c], acc);
    acc = fmaf(fv.z, fw[(k + 2) * 128 + c], acc);
    acc = fmaf(fv.w, fw[(k + 3) * 128 + c], acc);
  }
  out[gid] = fmaxf(fmaf(acc, fg[c] * kBNS, fb[c]), 0.f);
}

// ---------------------------------------------------------------------------
extern "C" void kernel_launch(void* const* d_in, const int* in_sizes, int n_in,
                              void* d_out, int out_size, void* d_ws, size_t ws_size,
                              hipStream_t stream) {
  (void)in_sizes; (void)n_in; (void)out_size; (void)ws_size;
  const float* pts = (const float*)d_in[0];
  const float* sf  = (const float*)d_in[1];
  const int*   vc  = (const int*)d_in[2];
  const float* vf  = (const float*)d_in[3];
  const float* raw_w0 = (const float*)d_in[4];
  const float* raw_g0 = (const float*)d_in[5];
  const float* raw_b0 = (const float*)d_in[6];
  const float* raw_w1 = (const float*)d_in[7];
  const float* raw_g1 = (const float*)d_in[8];
  const float* raw_b1 = (const float*)d_in[9];
  const float* conv_w0 = (const float*)d_in[10];
  const float* conv_g0 = (const float*)d_in[11];
  const float* conv_b0 = (const float*)d_in[12];
  const float* conv_w1 = (const float*)d_in[13];
  const float* conv_g1 = (const float*)d_in[14];
  const float* conv_b1 = (const float*)d_in[15];
  const float* fus_w = (const float*)d_in[16];
  const float* fus_g = (const float*)d_in[17];
  const float* fus_b = (const float*)d_in[18];
  float* out = (float*)d_out;

  float* W = (float*)d_ws;
  float* rx   = W;            // 32768
  float* ry   = W + 32768;
  float* rz   = W + 65536;
  float* rint = W + 98304;
  float* cx   = W + 131072;   // 16384 each
  float* cy   = W + 147456;
  float* cz   = W + 163840;
  float* kx   = W + 180224;   // 4096 each
  float* ky   = W + 184320;
  float* kz   = W + 188416;
  float* feats = W + 192512;  // 4096 * 416

  prep_kernel<<<128, 256, 0, stream>>>(pts, vc, rx, ry, rz, rint, cx, cy, cz);
  fps_kernel<<<2, 1024, 0, stream>>>(rx, ry, rz, kx, ky, kz);
  bev_kernel<<<NKPALL, 256, 0, stream>>>(sf, kx, ky, feats);
  raw_sa_kernel<<<2048, 256, 0, stream>>>(rx, ry, rz, rint, kx, ky, kz,
                                          raw_w0, raw_g0, raw_b0, raw_w1, raw_g1, raw_b1,
                                          feats);
  conv_sa_kernel<<<2048, 256, 0, stream>>>(cx, cy, cz, vf, kx, ky, kz,
                                           conv_w0, conv_g0, conv_b0, conv_w1, conv_g1, conv_b1,
                                           feats);
  fusion_kernel<<<2048, 256, 0, stream>>>(feats, fus_w, fus_g, fus_b, out);
}

// Round 3
// 3787.693 us; speedup vs baseline: 1.9027x; 1.6389x over previous
//
#include <hip/hip_runtime.h>

// ---------------------------------------------------------------------------
// VoxelSetAbstraction forward (PV-RCNN style) for MI355X
//   B=2, N_RAW=16384, N_KP=2048, M_VOX=8192, C_VOX=64
//   BEV: (2,256,200,176), stride 8, voxel 0.05, pc_min (0,-40,-3)
//   raw SA: radii (0.4,0.8) ns (16,16), MLP 4->16->16
//   conv SA: radii (1.2,2.4) ns (16,32), MLP 67->64->64
//   fusion: 416 -> 128
// ---------------------------------------------------------------------------

#define NRAW   16384
#define MVOX   8192
#define NKP    2048
#define NKPALL 4096   // B * NKP

__device__ __constant__ float kBNS = (float)0.9999950000374997; // 1/sqrt(1+1e-5)

// ---------------------------------------------------------------------------
// K0: transpose points to SoA + compute voxel centers
// ---------------------------------------------------------------------------
__global__ __launch_bounds__(256) void prep_kernel(
    const float* __restrict__ pts, const int* __restrict__ vc,
    float* __restrict__ rx, float* __restrict__ ry, float* __restrict__ rz,
    float* __restrict__ rint,
    float* __restrict__ cx, float* __restrict__ cy, float* __restrict__ cz) {
#pragma clang fp contract(off)
  int i = blockIdx.x * 256 + threadIdx.x;
  if (i < 2 * NRAW) {
    const float* p = pts + (size_t)i * 5;
    rx[i] = p[1]; ry[i] = p[2]; rz[i] = p[3]; rint[i] = p[4];
  }
  if (i < 2 * MVOX) {
    const int* v = vc + (size_t)i * 4;
    cx[i] = ((float)v[3] + 0.5f) * 0.2f + 0.0f;
    cy[i] = ((float)v[2] + 0.5f) * 0.2f + -40.0f;
    cz[i] = ((float)v[1] + 0.5f) * 0.4f + -3.0f;
  }
}

// ---------------------------------------------------------------------------
// Wave-wide u32 max via DPP (VALU pipe only, zero DS traffic).
// In-row: quad xor1, quad xor2, row_ror:4, row_ror:8 -> row max in all lanes.
// Cross-row: row_bcast15 (mask 0xa), row_bcast31 (mask 0xc) -> lane 63 total.
// Values must be >= 0 interpreted as u32 (0-fill is the identity for max).
// Returns the wave maximum (uniform, via readlane 63).
// ---------------------------------------------------------------------------
__device__ __forceinline__ unsigned wave_umax(unsigned v) {
  unsigned t;
  t = (unsigned)__builtin_amdgcn_update_dpp(0, (int)v, 0xB1,  0xf, 0xf, true); v = v > t ? v : t;
  t = (unsigned)__builtin_amdgcn_update_dpp(0, (int)v, 0x4E,  0xf, 0xf, true); v = v > t ? v : t;
  t = (unsigned)__builtin_amdgcn_update_dpp(0, (int)v, 0x124, 0xf, 0xf, true); v = v > t ? v : t;
  t = (unsigned)__builtin_amdgcn_update_dpp(0, (int)v, 0x128, 0xf, 0xf, true); v = v > t ? v : t;
  t = (unsigned)__builtin_amdgcn_update_dpp(0, (int)v, 0x142, 0xa, 0xf, true); v = v > t ? v : t;
  t = (unsigned)__builtin_amdgcn_update_dpp(0, (int)v, 0x143, 0xc, 0xf, true); v = v > t ? v : t;
  return (unsigned)__builtin_amdgcn_readlane((int)v, 63);
}

// ---------------------------------------------------------------------------
// K1: farthest point sampling. One block/batch, 1024 thr, 16 pts/thread.
// Per iteration (2047, strictly sequential):
//   - register dist-update + local first-argmax (contract off, numpy order)
//   - DPP two-phase wave argmax: umax(f32 bits) then umax(~idx) among tied
//     lanes (f32 bits of nonneg floats order as u32; ~idx max = min idx)
//   - lane0 writes packed (val||idx) u64 to LDS table (double-buffered),
//     ONE barrier, then every wave DPP-reduces the 16 entries redundantly
//   - winner coords fetched as wave-uniform (scalar) loads from global
// DS ops: 2/wave/iter (was ~58 with shfl_xor) -> off the DS-pipe bottleneck.
// ---------------------------------------------------------------------------
__global__ __launch_bounds__(1024, 4) void fps_kernel(
    const float* __restrict__ rx, const float* __restrict__ ry,
    const float* __restrict__ rz,
    float* __restrict__ kx, float* __restrict__ ky, float* __restrict__ kz) {
#pragma clang fp contract(off)
  const int b = blockIdx.x;
  const int t = threadIdx.x;
  const float* bxp = rx + b * NRAW;
  const float* byp = ry + b * NRAW;
  const float* bzp = rz + b * NRAW;

  float px[16], py[16], pz[16], dd[16];
#pragma unroll
  for (int j = 0; j < 16; ++j) {
    int p = j * 1024 + t;
    px[j] = bxp[p]; py[j] = byp[p]; pz[j] = bzp[p];
    dd[j] = 1e10f;
  }

  // winner state for iteration 0: point 0 (uniform broadcast load)
  float lx = bxp[0], ly = byp[0], lz = bzp[0];
  if (t == 0) { kx[b * NKP] = lx; ky[b * NKP] = ly; kz[b * NKP] = lz; }

  __shared__ unsigned long long tab[2][16];

  for (int s = 1; s < NKP; ++s) {
    const int buf = s & 1;
    float bv = -1.0f;
    int bi = 0;
#pragma unroll
    for (int j = 0; j < 16; ++j) {
      float dx = px[j] - lx, dy = py[j] - ly, dz = pz[j] - lz;
      float d2 = dx * dx; d2 = d2 + dy * dy; d2 = d2 + dz * dz;
      float nd = fminf(dd[j], d2);
      dd[j] = nd;
      bool c = nd > bv;                 // ascending j => first-idx tiebreak
      bv = c ? nd : bv;
      bi = c ? (j * 1024 + t) : bi;
    }
    // wave argmax: phase 1 value (bv >= 0 so f32 bits order as u32)
    const unsigned vb = __float_as_uint(bv);
    const unsigned vmax = wave_umax(vb);
    // phase 2: min index among value-tied lanes (umax of ~idx; 0 = no cand)
    const unsigned cand = (vb == vmax) ? ~(unsigned)bi : 0u;
    const unsigned cm = wave_umax(cand);
    const unsigned widx = ~cm;

    if ((t & 63) == 0)
      tab[buf][t >> 6] = ((unsigned long long)vmax << 32) | widx;
    __syncthreads();

    // block argmax over 16 wave winners, done redundantly by every wave
    const unsigned long long pk = tab[buf][t & 15];
    const unsigned hi = (unsigned)(pk >> 32), lo = (unsigned)pk;
    const unsigned gh = wave_umax(hi);
    const unsigned cand2 = (hi == gh) ? ~lo : 0u;
    const unsigned gl = wave_umax(cand2);
    const int wi = __builtin_amdgcn_readfirstlane((int)~gl);

    lx = bxp[wi]; ly = byp[wi]; lz = bzp[wi];   // uniform (scalar) loads
    if (t == 0) { kx[b * NKP + s] = lx; ky[b * NKP + s] = ly; kz[b * NKP + s] = lz; }
    // no second barrier: next iter writes the other LDS buffer; a wave
    // cannot be >1 barrier ahead, so reads of buf finish before re-write.
  }
}

// ---------------------------------------------------------------------------
// K2: BEV bilinear. one block per keypoint, 256 threads = 256 channels.
// ---------------------------------------------------------------------------
__global__ __launch_bounds__(256) void bev_kernel(
    const float* __restrict__ sf, const float* __restrict__ kx,
    const float* __restrict__ ky, float* __restrict__ feats) {
#pragma clang fp contract(off)
  const int kidx = blockIdx.x;
  const int c = threadIdx.x;
  const int b = kidx >> 11;
  const float x = (kx[kidx] - 0.0f) / 0.05f / 8.0f;
  const float y = (ky[kidx] - (-40.0f)) / 0.05f / 8.0f;
  const float xf = floorf(x), yf = floorf(y);
  int x0 = (int)xf;     x0 = x0 < 0 ? 0 : (x0 > 175 ? 175 : x0);
  int x1 = (int)xf + 1; x1 = x1 < 0 ? 0 : (x1 > 175 ? 175 : x1);
  int y0 = (int)yf;     y0 = y0 < 0 ? 0 : (y0 > 199 ? 199 : y0);
  int y1 = (int)yf + 1; y1 = y1 < 0 ? 0 : (y1 > 199 ? 199 : y1);
  const float x0f = (float)x0, x1f = (float)x1, y0f = (float)y0, y1f = (float)y1;
  const float wa = (x - x0f) * (y1f - y);
  const float wb = (x1f - x) * (y1f - y);
  const float wc = (x1f - x) * (y - y0f);
  const float wd = (x - x0f) * (y - y0f);
  const float* base = sf + ((size_t)b * 256 + c) * (200 * 176);
  const float fa = base[y1 * 176 + x0];
  const float fb = base[y1 * 176 + x1];
  const float fc = base[y0 * 176 + x1];
  const float fd = base[y0 * 176 + x0];
  float r = fd * wb; r = r + fc * wa; r = r + fa * wc; r = r + fb * wd;
  feats[(size_t)kidx * 416 + c] = r;
}

// ---------------------------------------------------------------------------
// K3: raw SA. one wave per (keypoint, radius). MLP 4->16->16, max-pool.
// ---------------------------------------------------------------------------
__global__ __launch_bounds__(256) void raw_sa_kernel(
    const float* __restrict__ rx, const float* __restrict__ ry,
    const float* __restrict__ rz, const float* __restrict__ rint,
    const float* __restrict__ kx, const float* __restrict__ ky,
    const float* __restrict__ kz,
    const float* __restrict__ w0, const float* __restrict__ g0,
    const float* __restrict__ b0, const float* __restrict__ w1,
    const float* __restrict__ g1, const float* __restrict__ b1,
    float* __restrict__ feats) {
  const int wv = threadIdx.x >> 6;
  const int lane = threadIdx.x & 63;
  const int gw = blockIdx.x * 4 + wv;       // 0..8191
  const int ri = gw >> 12;                  // radius index 0/1
  const int kidx = gw & 4095;
  const int b = kidx >> 11;
  const float R2 = ri ? (float)(0.8 * 0.8) : (float)(0.4 * 0.4);

  __shared__ int   idxl[4][16];
  __shared__ float hbuf[4][16][17];

  const float kxv = kx[kidx], kyv = ky[kidx], kzv = kz[kidx];
  const int base = b * NRAW;
  int cnt = 0;
  {
#pragma clang fp contract(off)
    for (int ch = 0; ch < NRAW / 64 && cnt < 16; ++ch) {
      const int p = base + ch * 64 + lane;
      float dx = kxv - rx[p], dy = kyv - ry[p], dz = kzv - rz[p];
      float d2 = dx * dx; d2 = d2 + dy * dy; d2 = d2 + dz * dz;
      unsigned long long m = __ballot(d2 < R2);
      while (m && cnt < 16) {
        int bit = __builtin_ctzll(m);
        if (lane == 0) idxl[wv][cnt] = ch * 64 + bit;
        ++cnt;
        m &= m - 1;
      }
    }
  }
  const int outoff = kidx * 416 + 256 + ri * 16;
  if (cnt == 0) {
    if (lane < 16) feats[outoff + lane] = 0.f;
    return;
  }
  __threadfence_block();

  const int s = lane & 15, cq = lane >> 4;
  const int ss = (s < cnt) ? s : 0;          // duplicate sample 0 (matches ref pad)
  const int p = base + idxl[wv][ss];
  const float gx = rx[p] - kxv, gy = ry[p] - kyv, gz = rz[p] - kzv, gi = rint[p];
  const int wb0 = ri * 64, cb = ri * 16;
#pragma unroll
  for (int j = 0; j < 4; ++j) {
    int c = cq * 4 + j;
    float a = gx * w0[wb0 + c];
    a = fmaf(gy, w0[wb0 + 16 + c], a);
    a = fmaf(gz, w0[wb0 + 32 + c], a);
    a = fmaf(gi, w0[wb0 + 48 + c], a);
    a = fmaf(a, g0[cb + c] * kBNS, b0[cb + c]);
    hbuf[wv][s][c] = fmaxf(a, 0.f);
  }
  __threadfence_block();
  float o0 = 0.f, o1 = 0.f, o2 = 0.f, o3 = 0.f;
  const int wb1 = ri * 256;
#pragma unroll
  for (int k = 0; k < 16; ++k) {
    float hk = hbuf[wv][s][k];
    o0 = fmaf(hk, w1[wb1 + k * 16 + cq * 4 + 0], o0);
    o1 = fmaf(hk, w1[wb1 + k * 16 + cq * 4 + 1], o1);
    o2 = fmaf(hk, w1[wb1 + k * 16 + cq * 4 + 2], o2);
    o3 = fmaf(hk, w1[wb1 + k * 16 + cq * 4 + 3], o3);
  }
  float v0 = fmaxf(fmaf(o0, g1[cb + cq * 4 + 0] * kBNS, b1[cb + cq * 4 + 0]), 0.f);
  float v1 = fmaxf(fmaf(o1, g1[cb + cq * 4 + 1] * kBNS, b1[cb + cq * 4 + 1]), 0.f);
  float v2 = fmaxf(fmaf(o2, g1[cb + cq * 4 + 2] * kBNS, b1[cb + cq * 4 + 2]), 0.f);
  float v3 = fmaxf(fmaf(o3, g1[cb + cq * 4 + 3] * kBNS, b1[cb + cq * 4 + 3]), 0.f);
#pragma unroll
  for (int off = 1; off < 16; off <<= 1) {
    v0 = fmaxf(v0, __shfl_xor(v0, off, 64));
    v1 = fmaxf(v1, __shfl_xor(v1, off, 64));
    v2 = fmaxf(v2, __shfl_xor(v2, off, 64));
    v3 = fmaxf(v3, __shfl_xor(v3, off, 64));
  }
  if (s == 0) {
    feats[outoff + cq * 4 + 0] = v0;
    feats[outoff + cq * 4 + 1] = v1;
    feats[outoff + cq * 4 + 2] = v2;
    feats[outoff + cq * 4 + 3] = v3;
  }
}

// ---------------------------------------------------------------------------
// K4: conv SA. one wave per (keypoint, radius). MLP 67->64->64, max-pool.
// Weight columns live in VGPRs; grouped feature row broadcast via LDS.
// ---------------------------------------------------------------------------
__global__ __launch_bounds__(256) void conv_sa_kernel(
    const float* __restrict__ cx, const float* __restrict__ cy,
    const float* __restrict__ cz, const float* __restrict__ vf,
    const float* __restrict__ kx, const float* __restrict__ ky,
    const float* __restrict__ kz,
    const float* __restrict__ w0, const float* __restrict__ g0,
    const float* __restrict__ b0, const float* __restrict__ w1,
    const float* __restrict__ g1, const float* __restrict__ b1,
    float* __restrict__ feats) {
  const int wv = threadIdx.x >> 6;
  const int lane = threadIdx.x & 63;
  const int gw = blockIdx.x * 4 + wv;
  const int ri = gw >> 12;
  const int kidx = gw & 4095;
  const int b = kidx >> 11;
  const int NS = ri ? 32 : 16;
  const float R2 = ri ? (float)(2.4 * 2.4) : (float)(1.2 * 1.2);

  __shared__ int   idxl[4][32];
  __shared__ float gbuf[4][64];
  __shared__ float hbuf[4][32][64];

  const float kxv = kx[kidx], kyv = ky[kidx], kzv = kz[kidx];
  const int base = b * MVOX;
  int cnt = 0;
  {
#pragma clang fp contract(off)
    for (int ch = 0; ch < MVOX / 64 && cnt < NS; ++ch) {
      const int p = base + ch * 64 + lane;
      float dx = kxv - cx[p], dy = kyv - cy[p], dz = kzv - cz[p];
      float d2 = dx * dx; d2 = d2 + dy * dy; d2 = d2 + dz * dz;
      unsigned long long m = __ballot(d2 < R2);
      while (m && cnt < NS) {
        int bit = __builtin_ctzll(m);
        if (lane == 0) idxl[wv][cnt] = ch * 64 + bit;
        ++cnt;
        m &= m - 1;
      }
    }
  }
  const int outoff = kidx * 416 + 288 + ri * 64;
  if (cnt == 0) {
    feats[outoff + lane] = 0.f;
    return;
  }
  __threadfence_block();

  // per-lane weight columns (lane == output channel)
  const float wA0 = w0[(ri * 67 + 0) * 64 + lane];
  const float wA1 = w0[(ri * 67 + 1) * 64 + lane];
  const float wA2 = w0[(ri * 67 + 2) * 64 + lane];
  float wB[64];
#pragma unroll
  for (int k = 0; k < 64; ++k) wB[k] = w0[(ri * 67 + 3 + k) * 64 + lane];
  float wC[64];
#pragma unroll
  for (int k = 0; k < 64; ++k) wC[k] = w1[(ri * 64 + k) * 64 + lane];
  const float s0 = g0[ri * 64 + lane] * kBNS, bb0 = b0[ri * 64 + lane];
  const float s1 = g1[ri * 64 + lane] * kBNS, bb1 = b1[ri * 64 + lane];

  for (int sm = 0; sm < cnt; ++sm) {
    const int p = base + idxl[wv][sm];
    const float ox = cx[p] - kxv, oy = cy[p] - kyv, oz = cz[p] - kzv;
    gbuf[wv][lane] = vf[(size_t)p * 64 + lane];
    __threadfence_block();
    float acc = ox * wA0;
    acc = fmaf(oy, wA1, acc);
    acc = fmaf(oz, wA2, acc);
#pragma unroll
    for (int k4 = 0; k4 < 16; ++k4) {
      float4 g4 = *(const float4*)&gbuf[wv][k4 * 4];
      acc = fmaf(g4.x, wB[k4 * 4 + 0], acc);
      acc = fmaf(g4.y, wB[k4 * 4 + 1], acc);
      acc = fmaf(g4.z, wB[k4 * 4 + 2], acc);
      acc = fmaf(g4.w, wB[k4 * 4 + 3], acc);
    }
    hbuf[wv][sm][lane] = fmaxf(fmaf(acc, s0, bb0), 0.f);
    __threadfence_block();
  }
  float mx = -1e30f;
  for (int sm = 0; sm < cnt; ++sm) {
    float acc = 0.f;
#pragma unroll
    for (int k4 = 0; k4 < 16; ++k4) {
      float4 h4 = *(const float4*)&hbuf[wv][sm][k4 * 4];
      acc = fmaf(h4.x, wC[k4 * 4 + 0], acc);
      acc = fmaf(h4.y, wC[k4 * 4 + 1], acc);
      acc = fmaf(h4.z, wC[k4 * 4 + 2], acc);
      acc = fmaf(h4.w, wC[k4 * 4 + 3], acc);
    }
    mx = fmaxf(mx, fmaxf(fmaf(acc, s1, bb1), 0.f));
  }
  feats[outoff + lane] = mx;
}

// ---------------------------------------------------------------------------
// K5: fusion 416 -> 128 + BN + ReLU. one thread per (kp, out-channel).
// ---------------------------------------------------------------------------
__global__ __launch_bounds__(256) void fusion_kernel(
    const float* __restrict__ feats, const float* __restrict__ fw,
    const float* __restrict__ fg, const float* __restrict__ fb,
    float* __restrict__ out) {
  const int gid = blockIdx.x * 256 + threadIdx.x;
  const int kidx = gid >> 7, c = gid & 127;
  const float* f = feats + (size_t)kidx * 416;
  float acc = 0.f;
#pragma unroll 4
  for (int k = 0; k < 416; k += 4) {
    float4 fv = *(const float4*)(f + k);
    acc = fmaf(fv.x, fw[(k + 0) * 128 + c], acc);
    acc = fmaf(fv.y, fw[(k + 1) * 128 + c], acc);
    acc = fmaf(fv.z, fw[(k + 2) * 128 + c], acc);
    acc = fmaf(fv.w, fw[(k + 3) * 128 + c], acc);
  }
  out[gid] = fmaxf(fmaf(acc, fg[c] * kBNS, fb[c]), 0.f);
}

// ---------------------------------------------------------------------------
extern "C" void kernel_launch(void* const* d_in, const int* in_sizes, int n_in,
                              void* d_out, int out_size, void* d_ws, size_t ws_size,
                              hipStream_t stream) {
  (void)in_sizes; (void)n_in; (void)out_size; (void)ws_size;
  const float* pts = (const float*)d_in[0];
  const float* sf  = (const float*)d_in[1];
  const int*   vc  = (const int*)d_in[2];
  const float* vf  = (const float*)d_in[3];
  const float* raw_w0 = (const float*)d_in[4];
  const float* raw_g0 = (const float*)d_in[5];
  const float* raw_b0 = (const float*)d_in[6];
  const float* raw_w1 = (const float*)d_in[7];
  const float* raw_g1 = (const float*)d_in[8];
  const float* raw_b1 = (const float*)d_in[9];
  const float* conv_w0 = (const float*)d_in[10];
  const float* conv_g0 = (const float*)d_in[11];
  const float* conv_b0 = (const float*)d_in[12];
  const float* conv_w1 = (const float*)d_in[13];
  const float* conv_g1 = (const float*)d_in[14];
  const float* conv_b1 = (const float*)d_in[15];
  const float* fus_w = (const float*)d_in[16];
  const float* fus_g = (const float*)d_in[17];
  const float* fus_b = (const float*)d_in[18];
  float* out = (float*)d_out;

  float* W = (float*)d_ws;
  float* rx   = W;            // 32768
  float* ry   = W + 32768;
  float* rz   = W + 65536;
  float* rint = W + 98304;
  float* cx   = W + 131072;   // 16384 each
  float* cy   = W + 147456;
  float* cz   = W + 163840;
  float* kx   = W + 180224;   // 4096 each
  float* ky   = W + 184320;
  float* kz   = W + 188416;
  float* feats = W + 192512;  // 4096 * 416

  prep_kernel<<<128, 256, 0, stream>>>(pts, vc, rx, ry, rz, rint, cx, cy, cz);
  fps_kernel<<<2, 1024, 0, stream>>>(rx, ry, rz, kx, ky, kz);
  bev_kernel<<<NKPALL, 256, 0, stream>>>(sf, kx, ky, feats);
  raw_sa_kernel<<<2048, 256, 0, stream>>>(rx, ry, rz, rint, kx, ky, kz,
                                          raw_w0, raw_g0, raw_b0, raw_w1, raw_g1, raw_b1,
                                          feats);
  conv_sa_kernel<<<2048, 256, 0, stream>>>(cx, cy, cz, vf, kx, ky, kz,
                                           conv_w0, conv_g0, conv_b0, conv_w1, conv_g1, conv_b1,
                                           feats);
  fusion_kernel<<<2048, 256, 0, stream>>>(feats, fus_w, fus_g, fus_b, out);
}

// Round 4
// 3372.487 us; speedup vs baseline: 2.1369x; 1.1231x over previous
//
#include <hip/hip_runtime.h>

// ---------------------------------------------------------------------------
// VoxelSetAbstraction forward (PV-RCNN style) for MI355X
//   B=2, N_RAW=16384, N_KP=2048, M_VOX=8192, C_VOX=64
//   BEV: (2,256,200,176), stride 8, voxel 0.05, pc_min (0,-40,-3)
//   raw SA: radii (0.4,0.8) ns (16,16), MLP 4->16->16
//   conv SA: radii (1.2,2.4) ns (16,32), MLP 67->64->64
//   fusion: 416 -> 128
// ---------------------------------------------------------------------------

#define NRAW   16384
#define MVOX   8192
#define NKP    2048
#define NKPALL 4096   // B * NKP

typedef float v2f __attribute__((ext_vector_type(2)));

__device__ __constant__ float kBNS = (float)0.9999950000374997; // 1/sqrt(1+1e-5)

// ---------------------------------------------------------------------------
// K0: transpose points to SoA + compute voxel centers
// ---------------------------------------------------------------------------
__global__ __launch_bounds__(256) void prep_kernel(
    const float* __restrict__ pts, const int* __restrict__ vc,
    float* __restrict__ rx, float* __restrict__ ry, float* __restrict__ rz,
    float* __restrict__ rint,
    float* __restrict__ cx, float* __restrict__ cy, float* __restrict__ cz) {
#pragma clang fp contract(off)
  int i = blockIdx.x * 256 + threadIdx.x;
  if (i < 2 * NRAW) {
    const float* p = pts + (size_t)i * 5;
    rx[i] = p[1]; ry[i] = p[2]; rz[i] = p[3]; rint[i] = p[4];
  }
  if (i < 2 * MVOX) {
    const int* v = vc + (size_t)i * 4;
    cx[i] = ((float)v[3] + 0.5f) * 0.2f + 0.0f;
    cy[i] = ((float)v[2] + 0.5f) * 0.2f + -40.0f;
    cz[i] = ((float)v[1] + 0.5f) * 0.4f + -3.0f;
  }
}

// ---------------------------------------------------------------------------
// Wave-wide u32 max via DPP (VALU pipe, zero DS). After 6 stages lane 63
// holds the wave max (other lanes partial). Values must be >= 0 as u32.
// ---------------------------------------------------------------------------
__device__ __forceinline__ unsigned wave_umax63(unsigned v) {
  unsigned t;
  t = (unsigned)__builtin_amdgcn_update_dpp(0, (int)v, 0xB1,  0xf, 0xf, true); v = v > t ? v : t;
  t = (unsigned)__builtin_amdgcn_update_dpp(0, (int)v, 0x4E,  0xf, 0xf, true); v = v > t ? v : t;
  t = (unsigned)__builtin_amdgcn_update_dpp(0, (int)v, 0x124, 0xf, 0xf, true); v = v > t ? v : t;
  t = (unsigned)__builtin_amdgcn_update_dpp(0, (int)v, 0x128, 0xf, 0xf, true); v = v > t ? v : t;
  t = (unsigned)__builtin_amdgcn_update_dpp(0, (int)v, 0x142, 0xa, 0xf, true); v = v > t ? v : t;
  t = (unsigned)__builtin_amdgcn_update_dpp(0, (int)v, 0x143, 0xc, 0xf, true); v = v > t ? v : t;
  return v;  // valid in lane 63
}

// Max over 8 values replicated per 16-lane row (lane reads entry t&7):
// 3 in-row DPP stages -> every lane holds the max.
__device__ __forceinline__ unsigned row8_umax(unsigned v) {
  unsigned t;
  t = (unsigned)__builtin_amdgcn_update_dpp(0, (int)v, 0xB1,  0xf, 0xf, true); v = v > t ? v : t;
  t = (unsigned)__builtin_amdgcn_update_dpp(0, (int)v, 0x4E,  0xf, 0xf, true); v = v > t ? v : t;
  t = (unsigned)__builtin_amdgcn_update_dpp(0, (int)v, 0x124, 0xf, 0xf, true); v = v > t ? v : t;
  return v;  // uniform across the wave (entries replicated every 8 lanes)
}

// ---------------------------------------------------------------------------
// K1: farthest point sampling. One block/batch, 512 thr, 32 pts/thread held
// as 16 float2 pairs (VOP3P packed f32: pk_add/pk_mul are bit-identical to
// scalar, 2 elems/instr; contract(off) forbids pk_fma so numpy order holds).
// Pair jj: .x = point jj*512+t, .y = point (jj+16)*512+t.
// Per iteration: dist min-update (no index tracking), fmax tree -> bv;
// wave DPP umax -> lane63 writes tab[wave]; B1; 3-stage row reduce -> block
// max gh; ONLY lanes with bits(bv)==gh (typically 1 in the block; other
// waves s_cbranch_execz) scan registers descending for the first matching
// global index and atomicMin it into slot[buf]; B2; all read slot -> s_load
// winner coords. First-index tiebreak exact at every level.
// ---------------------------------------------------------------------------
__global__ __launch_bounds__(512, 2) void fps_kernel(
    const float* __restrict__ rx, const float* __restrict__ ry,
    const float* __restrict__ rz,
    float* __restrict__ kx, float* __restrict__ ky, float* __restrict__ kz) {
#pragma clang fp contract(off)
  const int b = blockIdx.x;
  const int t = threadIdx.x;
  const float* bxp = rx + b * NRAW;
  const float* byp = ry + b * NRAW;
  const float* bzp = rz + b * NRAW;

  v2f px2[16], py2[16], pz2[16], dd2[16];
#pragma unroll
  for (int jj = 0; jj < 16; ++jj) {
    const int pA = jj * 512 + t, pB = pA + 8192;
    px2[jj] = (v2f){bxp[pA], bxp[pB]};
    py2[jj] = (v2f){byp[pA], byp[pB]};
    pz2[jj] = (v2f){bzp[pA], bzp[pB]};
    dd2[jj] = (v2f){1e10f, 1e10f};
  }

  float lx = bxp[0], ly = byp[0], lz = bzp[0];
  if (t == 0) { kx[b * NKP] = lx; ky[b * NKP] = ly; kz[b * NKP] = lz; }

  __shared__ unsigned tab[8];      // per-wave max (value bits)
  __shared__ unsigned slot[2];     // atomicMin'd winner index, double-buffered
  if (t < 2) slot[t] = 0xFFFFFFFFu;

  for (int s = 1; s < NKP; ++s) {
    const int buf = s & 1;
    const v2f lxx = (v2f){lx, lx}, lyy = (v2f){ly, ly}, lzz = (v2f){lz, lz};
#pragma unroll
    for (int jj = 0; jj < 16; ++jj) {
      v2f dx = px2[jj] - lxx;
      v2f dy = py2[jj] - lyy;
      v2f dz = pz2[jj] - lzz;
      v2f d2 = dx * dx;
      d2 = d2 + dy * dy;
      d2 = d2 + dz * dz;
      v2f nd;
      nd.x = fminf(dd2[jj].x, d2.x);
      nd.y = fminf(dd2[jj].y, d2.y);
      dd2[jj] = nd;
    }
    // max tree over the 32 residual distances (compiler forms v_max3)
    float m0 = fmaxf(fmaxf(dd2[0].x, dd2[0].y), fmaxf(dd2[1].x, dd2[1].y));
    float m1 = fmaxf(fmaxf(dd2[2].x, dd2[2].y), fmaxf(dd2[3].x, dd2[3].y));
    float m2 = fmaxf(fmaxf(dd2[4].x, dd2[4].y), fmaxf(dd2[5].x, dd2[5].y));
    float m3 = fmaxf(fmaxf(dd2[6].x, dd2[6].y), fmaxf(dd2[7].x, dd2[7].y));
    float m4 = fmaxf(fmaxf(dd2[8].x, dd2[8].y), fmaxf(dd2[9].x, dd2[9].y));
    float m5 = fmaxf(fmaxf(dd2[10].x, dd2[10].y), fmaxf(dd2[11].x, dd2[11].y));
    float m6 = fmaxf(fmaxf(dd2[12].x, dd2[12].y), fmaxf(dd2[13].x, dd2[13].y));
    float m7 = fmaxf(fmaxf(dd2[14].x, dd2[14].y), fmaxf(dd2[15].x, dd2[15].y));
    const float bv = fmaxf(fmaxf(fmaxf(m0, m1), fmaxf(m2, m3)),
                           fmaxf(fmaxf(m4, m5), fmaxf(m6, m7)));

    const unsigned vb = __float_as_uint(bv);
    const unsigned wmax = wave_umax63(vb);
    if ((t & 63) == 63) tab[t >> 6] = wmax;   // lane 63 holds the wave max
    __syncthreads();                           // B1

    const unsigned gh = row8_umax(tab[t & 7]); // block max, all lanes
    if (t == 0) slot[1 - buf] = 0xFFFFFFFFu;   // reset other slot for next iter
    if (vb == gh) {                            // rare: winner lane(s) only
      int bi = 0;
#pragma unroll
      for (int jj = 15; jj >= 0; --jj)         // high half first (j = jj+16)
        if (__float_as_uint(dd2[jj].y) == gh) bi = (jj + 16) * 512 + t;
#pragma unroll
      for (int jj = 15; jj >= 0; --jj)         // low half (j = jj) wins ties
        if (__float_as_uint(dd2[jj].x) == gh) bi = jj * 512 + t;
      atomicMin(&slot[buf], (unsigned)bi);
    }
    __syncthreads();                           // B2

    const int wi = __builtin_amdgcn_readfirstlane((int)slot[buf]);
    lx = bxp[wi]; ly = byp[wi]; lz = bzp[wi];  // uniform (scalar) loads
    if (t == 0) { kx[b * NKP + s] = lx; ky[b * NKP + s] = ly; kz[b * NKP + s] = lz; }
  }
}

// ---------------------------------------------------------------------------
// K2: BEV bilinear. one block per keypoint, 256 threads = 256 channels.
// ---------------------------------------------------------------------------
__global__ __launch_bounds__(256) void bev_kernel(
    const float* __restrict__ sf, const float* __restrict__ kx,
    const float* __restrict__ ky, float* __restrict__ feats) {
#pragma clang fp contract(off)
  const int kidx = blockIdx.x;
  const int c = threadIdx.x;
  const int b = kidx >> 11;
  const float x = (kx[kidx] - 0.0f) / 0.05f / 8.0f;
  const float y = (ky[kidx] - (-40.0f)) / 0.05f / 8.0f;
  const float xf = floorf(x), yf = floorf(y);
  int x0 = (int)xf;     x0 = x0 < 0 ? 0 : (x0 > 175 ? 175 : x0);
  int x1 = (int)xf + 1; x1 = x1 < 0 ? 0 : (x1 > 175 ? 175 : x1);
  int y0 = (int)yf;     y0 = y0 < 0 ? 0 : (y0 > 199 ? 199 : y0);
  int y1 = (int)yf + 1; y1 = y1 < 0 ? 0 : (y1 > 199 ? 199 : y1);
  const float x0f = (float)x0, x1f = (float)x1, y0f = (float)y0, y1f = (float)y1;
  const float wa = (x - x0f) * (y1f - y);
  const float wb = (x1f - x) * (y1f - y);
  const float wc = (x1f - x) * (y - y0f);
  const float wd = (x - x0f) * (y - y0f);
  const float* base = sf + ((size_t)b * 256 + c) * (200 * 176);
  const float fa = base[y1 * 176 + x0];
  const float fb = base[y1 * 176 + x1];
  const float fc = base[y0 * 176 + x1];
  const float fd = base[y0 * 176 + x0];
  float r = fd * wb; r = r + fc * wa; r = r + fa * wc; r = r + fb * wd;
  feats[(size_t)kidx * 416 + c] = r;
}

// ---------------------------------------------------------------------------
// K3: raw SA. one wave per (keypoint, radius). MLP 4->16->16, max-pool.
// ---------------------------------------------------------------------------
__global__ __launch_bounds__(256) void raw_sa_kernel(
    const float* __restrict__ rx, const float* __restrict__ ry,
    const float* __restrict__ rz, const float* __restrict__ rint,
    const float* __restrict__ kx, const float* __restrict__ ky,
    const float* __restrict__ kz,
    const float* __restrict__ w0, const float* __restrict__ g0,
    const float* __restrict__ b0, const float* __restrict__ w1,
    const float* __restrict__ g1, const float* __restrict__ b1,
    float* __restrict__ feats) {
  const int wv = threadIdx.x >> 6;
  const int lane = threadIdx.x & 63;
  const int gw = blockIdx.x * 4 + wv;       // 0..8191
  const int ri = gw >> 12;                  // radius index 0/1
  const int kidx = gw & 4095;
  const int b = kidx >> 11;
  const float R2 = ri ? (float)(0.8 * 0.8) : (float)(0.4 * 0.4);

  __shared__ int   idxl[4][16];
  __shared__ float hbuf[4][16][17];

  const float kxv = kx[kidx], kyv = ky[kidx], kzv = kz[kidx];
  const int base = b * NRAW;
  int cnt = 0;
  {
#pragma clang fp contract(off)
    for (int ch = 0; ch < NRAW / 64 && cnt < 16; ++ch) {
      const int p = base + ch * 64 + lane;
      float dx = kxv - rx[p], dy = kyv - ry[p], dz = kzv - rz[p];
      float d2 = dx * dx; d2 = d2 + dy * dy; d2 = d2 + dz * dz;
      unsigned long long m = __ballot(d2 < R2);
      while (m && cnt < 16) {
        int bit = __builtin_ctzll(m);
        if (lane == 0) idxl[wv][cnt] = ch * 64 + bit;
        ++cnt;
        m &= m - 1;
      }
    }
  }
  const int outoff = kidx * 416 + 256 + ri * 16;
  if (cnt == 0) {
    if (lane < 16) feats[outoff + lane] = 0.f;
    return;
  }
  __threadfence_block();

  const int s = lane & 15, cq = lane >> 4;
  const int ss = (s < cnt) ? s : 0;          // duplicate sample 0 (matches ref pad)
  const int p = base + idxl[wv][ss];
  const float gx = rx[p] - kxv, gy = ry[p] - kyv, gz = rz[p] - kzv, gi = rint[p];
  const int wb0 = ri * 64, cb = ri * 16;
#pragma unroll
  for (int j = 0; j < 4; ++j) {
    int c = cq * 4 + j;
    float a = gx * w0[wb0 + c];
    a = fmaf(gy, w0[wb0 + 16 + c], a);
    a = fmaf(gz, w0[wb0 + 32 + c], a);
    a = fmaf(gi, w0[wb0 + 48 + c], a);
    a = fmaf(a, g0[cb + c] * kBNS, b0[cb + c]);
    hbuf[wv][s][c] = fmaxf(a, 0.f);
  }
  __threadfence_block();
  float o0 = 0.f, o1 = 0.f, o2 = 0.f, o3 = 0.f;
  const int wb1 = ri * 256;
#pragma unroll
  for (int k = 0; k < 16; ++k) {
    float hk = hbuf[wv][s][k];
    o0 = fmaf(hk, w1[wb1 + k * 16 + cq * 4 + 0], o0);
    o1 = fmaf(hk, w1[wb1 + k * 16 + cq * 4 + 1], o1);
    o2 = fmaf(hk, w1[wb1 + k * 16 + cq * 4 + 2], o2);
    o3 = fmaf(hk, w1[wb1 + k * 16 + cq * 4 + 3], o3);
  }
  float v0 = fmaxf(fmaf(o0, g1[cb + cq * 4 + 0] * kBNS, b1[cb + cq * 4 + 0]), 0.f);
  float v1 = fmaxf(fmaf(o1, g1[cb + cq * 4 + 1] * kBNS, b1[cb + cq * 4 + 1]), 0.f);
  float v2 = fmaxf(fmaf(o2, g1[cb + cq * 4 + 2] * kBNS, b1[cb + cq * 4 + 2]), 0.f);
  float v3 = fmaxf(fmaf(o3, g1[cb + cq * 4 + 3] * kBNS, b1[cb + cq * 4 + 3]), 0.f);
#pragma unroll
  for (int off = 1; off < 16; off <<= 1) {
    v0 = fmaxf(v0, __shfl_xor(v0, off, 64));
    v1 = fmaxf(v1, __shfl_xor(v1, off, 64));
    v2 = fmaxf(v2, __shfl_xor(v2, off, 64));
    v3 = fmaxf(v3, __shfl_xor(v3, off, 64));
  }
  if (s == 0) {
    feats[outoff + cq * 4 + 0] = v0;
    feats[outoff + cq * 4 + 1] = v1;
    feats[outoff + cq * 4 + 2] = v2;
    feats[outoff + cq * 4 + 3] = v3;
  }
}

// ---------------------------------------------------------------------------
// K4: conv SA. one wave per (keypoint, radius). MLP 67->64->64, max-pool.
// Weight columns live in VGPRs; grouped feature row broadcast via LDS.
// ---------------------------------------------------------------------------
__global__ __launch_bounds__(256) void conv_sa_kernel(
    const float* __restrict__ cx, const float* __restrict__ cy,
    const float* __restrict__ cz, const float* __restrict__ vf,
    const float* __restrict__ kx, const float* __restrict__ ky,
    const float* __restrict__ kz,
    const float* __restrict__ w0, const float* __restrict__ g0,
    const float* __restrict__ b0, const float* __restrict__ w1,
    const float* __restrict__ g1, const float* __restrict__ b1,
    float* __restrict__ feats) {
  const int wv = threadIdx.x >> 6;
  const int lane = threadIdx.x & 63;
  const int gw = blockIdx.x * 4 + wv;
  const int ri = gw >> 12;
  const int kidx = gw & 4095;
  const int b = kidx >> 11;
  const int NS = ri ? 32 : 16;
  const float R2 = ri ? (float)(2.4 * 2.4) : (float)(1.2 * 1.2);

  __shared__ int   idxl[4][32];
  __shared__ float gbuf[4][64];
  __shared__ float hbuf[4][32][64];

  const float kxv = kx[kidx], kyv = ky[kidx], kzv = kz[kidx];
  const int base = b * MVOX;
  int cnt = 0;
  {
#pragma clang fp contract(off)
    for (int ch = 0; ch < MVOX / 64 && cnt < NS; ++ch) {
      const int p = base + ch * 64 + lane;
      float dx = kxv - cx[p], dy = kyv - cy[p], dz = kzv - cz[p];
      float d2 = dx * dx; d2 = d2 + dy * dy; d2 = d2 + dz * dz;
      unsigned long long m = __ballot(d2 < R2);
      while (m && cnt < NS) {
        int bit = __builtin_ctzll(m);
        if (lane == 0) idxl[wv][cnt] = ch * 64 + bit;
        ++cnt;
        m &= m - 1;
      }
    }
  }
  const int outoff = kidx * 416 + 288 + ri * 64;
  if (cnt == 0) {
    feats[outoff + lane] = 0.f;
    return;
  }
  __threadfence_block();

  // per-lane weight columns (lane == output channel)
  const float wA0 = w0[(ri * 67 + 0) * 64 + lane];
  const float wA1 = w0[(ri * 67 + 1) * 64 + lane];
  const float wA2 = w0[(ri * 67 + 2) * 64 + lane];
  float wB[64];
#pragma unroll
  for (int k = 0; k < 64; ++k) wB[k] = w0[(ri * 67 + 3 + k) * 64 + lane];
  float wC[64];
#pragma unroll
  for (int k = 0; k < 64; ++k) wC[k] = w1[(ri * 64 + k) * 64 + lane];
  const float s0 = g0[ri * 64 + lane] * kBNS, bb0 = b0[ri * 64 + lane];
  const float s1 = g1[ri * 64 + lane] * kBNS, bb1 = b1[ri * 64 + lane];

  for (int sm = 0; sm < cnt; ++sm) {
    const int p = base + idxl[wv][sm];
    const float ox = cx[p] - kxv, oy = cy[p] - kyv, oz = cz[p] - kzv;
    gbuf[wv][lane] = vf[(size_t)p * 64 + lane];
    __threadfence_block();
    float acc = ox * wA0;
    acc = fmaf(oy, wA1, acc);
    acc = fmaf(oz, wA2, acc);
#pragma unroll
    for (int k4 = 0; k4 < 16; ++k4) {
      float4 g4 = *(const float4*)&gbuf[wv][k4 * 4];
      acc = fmaf(g4.x, wB[k4 * 4 + 0], acc);
      acc = fmaf(g4.y, wB[k4 * 4 + 1], acc);
      acc = fmaf(g4.z, wB[k4 * 4 + 2], acc);
      acc = fmaf(g4.w, wB[k4 * 4 + 3], acc);
    }
    hbuf[wv][sm][lane] = fmaxf(fmaf(acc, s0, bb0), 0.f);
    __threadfence_block();
  }
  float mx = -1e30f;
  for (int sm = 0; sm < cnt; ++sm) {
    float acc = 0.f;
#pragma unroll
    for (int k4 = 0; k4 < 16; ++k4) {
      float4 h4 = *(const float4*)&hbuf[wv][sm][k4 * 4];
      acc = fmaf(h4.x, wC[k4 * 4 + 0], acc);
      acc = fmaf(h4.y, wC[k4 * 4 + 1], acc);
      acc = fmaf(h4.z, wC[k4 * 4 + 2], acc);
      acc = fmaf(h4.w, wC[k4 * 4 + 3], acc);
    }
    mx = fmaxf(mx, fmaxf(fmaf(acc, s1, bb1), 0.f));
  }
  feats[outoff + lane] = mx;
}

// ---------------------------------------------------------------------------
// K5: fusion 416 -> 128 + BN + ReLU. one thread per (kp, out-channel).
// ---------------------------------------------------------------------------
__global__ __launch_bounds__(256) void fusion_kernel(
    const float* __restrict__ feats, const float* __restrict__ fw,
    const float* __restrict__ fg, const float* __restrict__ fb,
    float* __restrict__ out) {
  const int gid = blockIdx.x * 256 + threadIdx.x;
  const int kidx = gid >> 7, c = gid & 127;
  const float* f = feats + (size_t)kidx * 416;
  float acc = 0.f;
#pragma unroll 4
  for (int k = 0; k < 416; k += 4) {
    float4 fv = *(const float4*)(f + k);
    acc = fmaf(fv.x, fw[(k + 0) * 128 + c], acc);
    acc = fmaf(fv.y, fw[(k + 1) * 128 + c], acc);
    acc = fmaf(fv.z, fw[(k + 2) * 128 + c], acc);
    acc = fmaf(fv.w, fw[(k + 3) * 128 + c], acc);
  }
  out[gid] = fmaxf(fmaf(acc, fg[c] * kBNS, fb[c]), 0.f);
}

// ---------------------------------------------------------------------------
extern "C" void kernel_launch(void* const* d_in, const int* in_sizes, int n_in,
                              void* d_out, int out_size, void* d_ws, size_t ws_size,
                              hipStream_t stream) {
  (void)in_sizes; (void)n_in; (void)out_size; (void)ws_size;
  const float* pts = (const float*)d_in[0];
  const float* sf  = (const float*)d_in[1];
  const int*   vc  = (const int*)d_in[2];
  const float* vf  = (const float*)d_in[3];
  const float* raw_w0 = (const float*)d_in[4];
  const float* raw_g0 = (const float*)d_in[5];
  const float* raw_b0 = (const float*)d_in[6];
  const float* raw_w1 = (const float*)d_in[7];
  const float* raw_g1 = (const float*)d_in[8];
  const float* raw_b1 = (const float*)d_in[9];
  const float* conv_w0 = (const float*)d_in[10];
  const float* conv_g0 = (const float*)d_in[11];
  const float* conv_b0 = (const float*)d_in[12];
  const float* conv_w1 = (const float*)d_in[13];
  const float* conv_g1 = (const float*)d_in[14];
  const float* conv_b1 = (const float*)d_in[15];
  const float* fus_w = (const float*)d_in[16];
  const float* fus_g = (const float*)d_in[17];
  const float* fus_b = (const float*)d_in[18];
  float* out = (float*)d_out;

  float* W = (float*)d_ws;
  float* rx   = W;            // 32768
  float* ry   = W + 32768;
  float* rz   = W + 65536;
  float* rint = W + 98304;
  float* cx   = W + 131072;   // 16384 each
  float* cy   = W + 147456;
  float* cz   = W + 163840;
  float* kx   = W + 180224;   // 4096 each
  float* ky   = W + 184320;
  float* kz   = W + 188416;
  float* feats = W + 192512;  // 4096 * 416

  prep_kernel<<<128, 256, 0, stream>>>(pts, vc, rx, ry, rz, rint, cx, cy, cz);
  fps_kernel<<<2, 512, 0, stream>>>(rx, ry, rz, kx, ky, kz);
  bev_kernel<<<NKPALL, 256, 0, stream>>>(sf, kx, ky, feats);
  raw_sa_kernel<<<2048, 256, 0, stream>>>(rx, ry, rz, rint, kx, ky, kz,
                                          raw_w0, raw_g0, raw_b0, raw_w1, raw_g1, raw_b1,
                                          feats);
  conv_sa_kernel<<<2048, 256, 0, stream>>>(cx, cy, cz, vf, kx, ky, kz,
                                           conv_w0, conv_g0, conv_b0, conv_w1, conv_g1, conv_b1,
                                           feats);
  fusion_kernel<<<2048, 256, 0, stream>>>(feats, fus_w, fus_g, fus_b, out);
}